// Round 1
// baseline (823.136 us; speedup 1.0000x reference)
//
#include <hip/hip_runtime.h>

// ---------------- workspace layout (float offsets) ----------------
#define WS_T1 0            // 512*128
#define WS_T2 65536        // 512*64
#define WS_WC 98304        // 1024*64
#define WS_Z  163840       // 64*64*1200
#define WS_GP 5079040      // 8*64*4096
#define WS_SP 7176192      // 8*64*64
// total 7208960 floats = ~27.5 MiB

// Chebyshev coefficients for log(x) on [0.5, 1.7]:
// x = 1.1*(1 + (6/11) u), u = (x - 1.1)/0.6, t = -0.2967425904
// log(x) = C0 + C1*T1(u) + sum_{k=2..14} ck*T_k(u), ck = -2 t^k / k
#define CHEB_C0 0.0109173f
#define CHEB_C1 0.5934852f

// ---------------- tiny naive matmul: C[MxN] = A[MxK] @ B[KxN] ----------------
__global__ __launch_bounds__(256) void mm_naive(const float* __restrict__ A,
                                                const float* __restrict__ B,
                                                float* __restrict__ C,
                                                int M, int K, int N) {
    int n = blockIdx.x * 16 + threadIdx.x;
    int m = blockIdx.y * 16 + threadIdx.y;
    if (m >= M || n >= N) return;
    float acc = 0.f;
    for (int k = 0; k < K; ++k) acc = fmaf(A[m * K + k], B[k * N + n], acc);
    C[m * N + n] = acc;
}

// ---------------- Z[b][o][t] = sum_n Wc[n][o] * x[b][n][t] ----------------
// grid (10 t-tiles, 64 b), block 512 (8 waves; wave w owns o in [8w, 8w+8))
__global__ __launch_bounds__(512) void zproj(const float* __restrict__ x,
                                             const float* __restrict__ Wc,
                                             float* __restrict__ Z) {
    __shared__ __attribute__((aligned(16))) float sx[32][128];
    const int b    = blockIdx.y;
    const int t0   = blockIdx.x * 128;
    const int tid  = threadIdx.x;
    const int lane = tid & 63;
    const int wv   = __builtin_amdgcn_readfirstlane(tid >> 6);  // wave id, uniform
    const float* xb    = x + (size_t)b * 1024 * 1200;
    const float* wbase = Wc + wv * 8;

    float2 acc[8];
#pragma unroll
    for (int j = 0; j < 8; ++j) acc[j] = make_float2(0.f, 0.f);

    for (int k0 = 0; k0 < 1024; k0 += 32) {
        __syncthreads();  // previous tile fully consumed
#pragma unroll
        for (int r = 0; r < 8; ++r) {
            int i = tid + r * 512;
            int kk = i >> 7, tt = i & 127;
            int t = t0 + tt;
            sx[kk][tt] = (t < 1200) ? xb[(k0 + kk) * 1200 + t] : 0.f;
        }
        __syncthreads();
#pragma unroll 4
        for (int kk = 0; kk < 32; ++kk) {
            const float2 bv = *(const float2*)&sx[kk][2 * lane];
            const float* wr = wbase + (k0 + kk) * 64;  // wave-uniform address
#pragma unroll
            for (int j = 0; j < 8; ++j) {
                float a = wr[j];
                acc[j].x = fmaf(a, bv.x, acc[j].x);
                acc[j].y = fmaf(a, bv.y, acc[j].y);
            }
        }
    }
    int t = t0 + 2 * lane;
#pragma unroll
    for (int j = 0; j < 8; ++j) {
        int o = wv * 8 + j;
        float* zp = Z + ((size_t)(b * 64 + o)) * 1200 + t;
        if (t + 1 < 1200)      *(float2*)zp = acc[j];
        else if (t < 1200)     *zp = acc[j].x;
    }
}

// ---------------- partial Gram + row sums over a 150-wide t-chunk ----------------
// grid (8 chunks, 64 b), block 256
__global__ __launch_bounds__(256) void gpart(const float* __restrict__ Z,
                                             float* __restrict__ Gp,
                                             float* __restrict__ sp) {
    __shared__ __attribute__((aligned(16))) float zt[150][68];  // [t][o], padded
    const int ch = blockIdx.x, b = blockIdx.y;
    const int t0 = ch * 150;
    const int tid = threadIdx.x;
    const float* zb = Z + (size_t)b * 64 * 1200;

    for (int i = tid; i < 9600; i += 256) {
        int o = i / 150, t = i - o * 150;
        zt[t][o] = zb[o * 1200 + t0 + t];
    }
    __syncthreads();

    if (tid < 64) {  // row sums for mean correction
        float s = 0.f;
        for (int t = 0; t < 150; ++t) s += zt[t][tid];
        sp[(ch * 64 + b) * 64 + tid] = s;
    }

    const int tx = tid & 15, ty = tid >> 4;
    float acc[4][4] = {};
    for (int t = 0; t < 150; ++t) {
        float4 a  = *(const float4*)&zt[t][4 * ty];
        float4 bb = *(const float4*)&zt[t][4 * tx];
        const float* ap = (const float*)&a;
        const float* bp = (const float*)&bb;
#pragma unroll
        for (int r = 0; r < 4; ++r)
#pragma unroll
            for (int c = 0; c < 4; ++c)
                acc[r][c] = fmaf(ap[r], bp[c], acc[r][c]);
    }
    float* gp = Gp + ((size_t)(ch * 64 + b) << 12);
#pragma unroll
    for (int r = 0; r < 4; ++r) {
        float4 v;
        float* vp = (float*)&v;
#pragma unroll
        for (int c = 0; c < 4; ++c) vp[c] = acc[r][c];
        *(float4*)&gp[(4 * ty + r) * 64 + 4 * tx] = v;
    }
}

// ---------------- per-batch: Y -> log(Y) via Chebyshev -> linear head ----------------
// grid 64, block 256
__global__ __launch_bounds__(256) void logeig_head(const float* __restrict__ Gp,
                                                   const float* __restrict__ sp,
                                                   const float* __restrict__ lw,
                                                   const float* __restrict__ lb,
                                                   float* __restrict__ out) {
    __shared__ __attribute__((aligned(16))) float BU[4096];
    __shared__ __attribute__((aligned(16))) float Bu0[4096];
    __shared__ __attribute__((aligned(16))) float Bu1[4096];
    __shared__ float svec[64];
    __shared__ float red[11 * 256];

    const int b = blockIdx.x, tid = threadIdx.x;

    if (tid < 64) {
        float s = 0.f;
#pragma unroll
        for (int c = 0; c < 8; ++c) s += sp[(c * 64 + b) * 64 + tid];
        svec[tid] = s;
    }
    __syncthreads();

    // reduce partial Grams, form U = (Y - 1.1 I)/0.6; S init = c0*I + c1*U
    float Sreg[16];
    const float inv1200 = 1.f / 1200.f, inv1199 = 1.f / 1199.f, invmw = 1.f / 0.6f;
#pragma unroll
    for (int r = 0; r < 16; ++r) {
        int e = tid + (r << 8);
        float g = 0.f;
#pragma unroll
        for (int c = 0; c < 8; ++c) g += Gp[((size_t)(c * 64 + b) << 12) + e];
        int row = e >> 6, col = e & 63;
        float y = (g - svec[row] * svec[col] * inv1200) * inv1199;
        float u = (y - (row == col ? 1.1f : 0.f)) * invmw;
        BU[e] = u;
        Sreg[r] = (row == col ? CHEB_C0 : 0.f) + CHEB_C1 * u;
    }
    __syncthreads();

    const float cks[13] = {
        -0.0880562f,   0.0174200f,  -0.0038769f,   0.00092038f, -0.000227598f,
         5.78903e-5f, -1.50312e-5f,  3.96481e-6f, -1.05887e-6f,  2.85647e-7f,
        -7.77005e-8f,  2.12837e-8f, -5.86469e-9f };

    const int tx = tid & 15, ty = tid >> 4;
    float* cur = BU;
    float* prev = BU;  // dummy at step 0 (subtrahend is I there)
    for (int step = 0; step < 13; ++step) {
        float* dst = (step == 0) ? Bu0 : (step == 1) ? Bu1 : prev;
        float acc[4][4] = {};
#pragma unroll 4
        for (int k = 0; k < 64; ++k) {
            float4 a  = *(const float4*)&BU[k * 64 + 4 * ty];   // U symmetric: row=col
            float4 bb = *(const float4*)&cur[k * 64 + 4 * tx];
            const float* ap = (const float*)&a;
            const float* bp = (const float*)&bb;
#pragma unroll
            for (int r = 0; r < 4; ++r)
#pragma unroll
                for (int c = 0; c < 4; ++c)
                    acc[r][c] = fmaf(ap[r], bp[c], acc[r][c]);
        }
#pragma unroll
        for (int r = 0; r < 4; ++r) {
            int base = (4 * ty + r) * 64 + 4 * tx;
            float4 v;
            float* vp = (float*)&v;
#pragma unroll
            for (int c = 0; c < 4; ++c) {
                float pv = (step == 0) ? ((4 * ty + r) == (4 * tx + c) ? 1.f : 0.f)
                                       : prev[base + c];
                vp[c] = 2.f * acc[r][c] - pv;
            }
            *(float4*)&dst[base] = v;
        }
        __syncthreads();
        float ck = cks[step];
#pragma unroll
        for (int r = 0; r < 16; ++r) Sreg[r] = fmaf(ck, dst[tid + (r << 8)], Sreg[r]);
        prev = cur;
        cur = dst;
        __syncthreads();
    }

    // fused linear head: out[b][j] = lb[j] + sum_i S[i] * lw[j*4096 + i]
    float p[11];
#pragma unroll
    for (int j = 0; j < 11; ++j) p[j] = 0.f;
#pragma unroll
    for (int r = 0; r < 16; ++r) {
        int e = tid + (r << 8);
        float sv = Sreg[r];
#pragma unroll
        for (int j = 0; j < 11; ++j) p[j] = fmaf(sv, lw[j * 4096 + e], p[j]);
    }
#pragma unroll
    for (int j = 0; j < 11; ++j) red[j * 256 + tid] = p[j];
    __syncthreads();
    for (int s2 = 128; s2 > 0; s2 >>= 1) {
        if (tid < s2)
            for (int j = 0; j < 11; ++j)
                red[j * 256 + tid] += red[j * 256 + tid + s2];
        __syncthreads();
    }
    if (tid < 11) out[b * 11 + tid] = red[tid * 256] + lb[tid];
}

extern "C" void kernel_launch(void* const* d_in, const int* in_sizes, int n_in,
                              void* d_out, int out_size, void* d_ws, size_t ws_size,
                              hipStream_t stream) {
    const float* x    = (const float*)d_in[0];
    const float* W1   = (const float*)d_in[1];
    const float* W2   = (const float*)d_in[2];
    const float* W3   = (const float*)d_in[3];
    const float* W4   = (const float*)d_in[4];
    const float* lw   = (const float*)d_in[5];
    const float* lb   = (const float*)d_in[6];
    float* out = (float*)d_out;

    float* ws = (float*)d_ws;
    float* T1 = ws + WS_T1;
    float* T2 = ws + WS_T2;
    float* Wc = ws + WS_WC;
    float* Z  = ws + WS_Z;
    float* Gp = ws + WS_GP;
    float* Sp = ws + WS_SP;

    dim3 b16(16, 16);
    // Wc = W1 @ W2 @ W3 @ W4  (fold small side first)
    mm_naive<<<dim3(128 / 16, 512 / 16), b16, 0, stream>>>(W2, W3, T1, 512, 256, 128);
    mm_naive<<<dim3(64 / 16, 512 / 16),  b16, 0, stream>>>(T1, W4, T2, 512, 128, 64);
    mm_naive<<<dim3(64 / 16, 1024 / 16), b16, 0, stream>>>(W1, T2, Wc, 1024, 512, 64);

    zproj<<<dim3(10, 64), 512, 0, stream>>>(x, Wc, Z);
    gpart<<<dim3(8, 64), 256, 0, stream>>>(Z, Gp, Sp);
    logeig_head<<<64, 256, 0, stream>>>(Gp, Sp, lw, lb, out);
}

// Round 2
// 766.627 us; speedup vs baseline: 1.0737x; 1.0737x over previous
//
#include <hip/hip_runtime.h>

// ---------------- workspace layout (float offsets) ----------------
#define WS_T1 0            // 512*128
#define WS_T2 65536        // 512*64
#define WS_WC 98304        // 1024*64
#define WS_GP 163840       // 19*64*4096 = 4980736
#define WS_SP 5144576      // 19*64*64   = 77824
// total 5222400 floats ~= 20.9 MiB

#define NCHUNK 19          // 19 chunks of 64 t cover 1200 (last chunk 48 valid)

// Chebyshev for log(x) on [0.5, 1.7]; x = 1.1 + 0.6u, t = -0.2967425904
#define CHEB_C0 0.0109173f
#define CHEB_C1 0.5934852f

// ---------------- tiny naive matmul: C[MxN] = A[MxK] @ B[KxN] ----------------
__global__ __launch_bounds__(256) void mm_naive(const float* __restrict__ A,
                                                const float* __restrict__ B,
                                                float* __restrict__ C,
                                                int M, int K, int N) {
    int n = blockIdx.x * 16 + threadIdx.x;
    int m = blockIdx.y * 16 + threadIdx.y;
    if (m >= M || n >= N) return;
    float acc = 0.f;
    for (int k = 0; k < K; ++k) acc = fmaf(A[m * K + k], B[k * N + n], acc);
    C[m * N + n] = acc;
}

// ---------------- fused Z-projection + partial Gram ----------------
// grid (19 t-chunks, 64 b), block 256 = 4 waves.
// Wave wv handles k in [256*wv, 256*wv+256) for all 64 o, lane owns t = ch*64+lane.
// Partials reduced in LDS, then 64-wide partial Gram + row sums written out.
__global__ __launch_bounds__(256) void zgram(const float* __restrict__ x,
                                             const float* __restrict__ Wc,
                                             float* __restrict__ Gp,
                                             float* __restrict__ Sp) {
    __shared__ __attribute__((aligned(16))) float zt[64][68];  // [t_local][o], pad 68
    const int ch = blockIdx.x, b = blockIdx.y;
    const int tid  = threadIdx.x;
    const int lane = tid & 63;
    const int wv   = __builtin_amdgcn_readfirstlane(tid >> 6);  // uniform wave id
    const int t  = ch * 64 + lane;
    const int tc = (t < 1200) ? t : 1199;  // clamp: duplicate read, zeroed later
    const float* xp = x + ((size_t)b * 1024 + (size_t)wv * 256) * 1200 + tc;
    const float* wp = Wc + wv * 256 * 64;  // wave-uniform -> scalar loads

    float acc[64];
#pragma unroll
    for (int j = 0; j < 64; ++j) acc[j] = 0.f;

    for (int k = 0; k < 256; ++k) {
        const float xv = xp[(size_t)k * 1200];
        const float* wr = wp + k * 64;
#pragma unroll
        for (int j = 0; j < 64; ++j) acc[j] = fmaf(wr[j], xv, acc[j]);
    }
    if (t >= 1200) {
#pragma unroll
        for (int j = 0; j < 64; ++j) acc[j] = 0.f;
    }

    // cross-wave k-reduction into one LDS tile (4 short phases)
    for (int w = 0; w < 4; ++w) {
        if (wv == w) {
            if (w == 0) {
#pragma unroll
                for (int j = 0; j < 64; ++j) zt[lane][j] = acc[j];
            } else {
#pragma unroll
                for (int j = 0; j < 64; ++j) zt[lane][j] += acc[j];
            }
        }
        __syncthreads();
    }

    // partial row sums (for mean centering)
    if (tid < 64) {
        float s = 0.f;
        for (int tt = 0; tt < 64; ++tt) s += zt[tt][tid];
        Sp[(ch * 64 + b) * 64 + tid] = s;
    }

    // partial Gram over this 64-t chunk: 4x4 outputs per thread
    const int tx = tid & 15, ty = tid >> 4;
    float g[4][4] = {};
    for (int tt = 0; tt < 64; ++tt) {
        float4 a  = *(const float4*)&zt[tt][4 * ty];
        float4 bb = *(const float4*)&zt[tt][4 * tx];
        const float* ap = (const float*)&a;
        const float* bp = (const float*)&bb;
#pragma unroll
        for (int r = 0; r < 4; ++r)
#pragma unroll
            for (int c = 0; c < 4; ++c)
                g[r][c] = fmaf(ap[r], bp[c], g[r][c]);
    }
    float* gp = Gp + ((size_t)(ch * 64 + b) << 12);
#pragma unroll
    for (int r = 0; r < 4; ++r) {
        float4 v;
        float* vp = (float*)&v;
#pragma unroll
        for (int c = 0; c < 4; ++c) vp[c] = g[r][c];
        *(float4*)&gp[(4 * ty + r) * 64 + 4 * tx] = v;
    }
}

// ---------------- per-batch: Y -> log(Y) via Chebyshev -> linear head ----------------
// grid 64, block 256
__global__ __launch_bounds__(256) void logeig_head(const float* __restrict__ Gp,
                                                   const float* __restrict__ sp,
                                                   const float* __restrict__ lw,
                                                   const float* __restrict__ lb,
                                                   float* __restrict__ out) {
    __shared__ __attribute__((aligned(16))) float BU[4096];
    __shared__ __attribute__((aligned(16))) float Bu0[4096];
    __shared__ __attribute__((aligned(16))) float Bu1[4096];
    __shared__ float svec[64];
    __shared__ float red[11 * 256];

    const int b = blockIdx.x, tid = threadIdx.x;

    if (tid < 64) {
        float s = 0.f;
        for (int c = 0; c < NCHUNK; ++c) s += sp[(c * 64 + b) * 64 + tid];
        svec[tid] = s;
    }
    __syncthreads();

    // reduce partial Grams, form U = (Y - 1.1 I)/0.6; S init = c0*I + c1*U
    float Sreg[16];
    const float inv1200 = 1.f / 1200.f, inv1199 = 1.f / 1199.f, invmw = 1.f / 0.6f;
#pragma unroll
    for (int r = 0; r < 16; ++r) {
        int e = tid + (r << 8);
        float gsum = 0.f;
        for (int c = 0; c < NCHUNK; ++c) gsum += Gp[((size_t)(c * 64 + b) << 12) + e];
        int row = e >> 6, col = e & 63;
        float y = (gsum - svec[row] * svec[col] * inv1200) * inv1199;
        float u = (y - (row == col ? 1.1f : 0.f)) * invmw;
        BU[e] = u;
        Sreg[r] = (row == col ? CHEB_C0 : 0.f) + CHEB_C1 * u;
    }
    __syncthreads();

    // ck = -2 t^k / k, k = 2..10 (truncation ~4e-7, far under threshold)
    const float cks[9] = {
        -0.0880562f,   0.0174200f,  -0.0038769f,   0.00092038f, -0.000227593f,
         5.78886e-5f, -1.50307e-5f,  3.96467e-6f, -1.05886e-6f };

    const int tx = tid & 15, ty = tid >> 4;
    float* cur = BU;
    float* prev = BU;  // dummy at step 0 (subtrahend is I there)
    for (int step = 0; step < 9; ++step) {
        float* dst = (step == 0) ? Bu0 : (step == 1) ? Bu1 : prev;
        float acc[4][4] = {};
#pragma unroll 4
        for (int k = 0; k < 64; ++k) {
            float4 a  = *(const float4*)&BU[k * 64 + 4 * ty];   // U symmetric
            float4 bb = *(const float4*)&cur[k * 64 + 4 * tx];
            const float* ap = (const float*)&a;
            const float* bp = (const float*)&bb;
#pragma unroll
            for (int r = 0; r < 4; ++r)
#pragma unroll
                for (int c = 0; c < 4; ++c)
                    acc[r][c] = fmaf(ap[r], bp[c], acc[r][c]);
        }
#pragma unroll
        for (int r = 0; r < 4; ++r) {
            int base = (4 * ty + r) * 64 + 4 * tx;
            float4 v;
            float* vp = (float*)&v;
#pragma unroll
            for (int c = 0; c < 4; ++c) {
                float pv = (step == 0) ? ((4 * ty + r) == (4 * tx + c) ? 1.f : 0.f)
                                       : prev[base + c];
                vp[c] = 2.f * acc[r][c] - pv;
            }
            *(float4*)&dst[base] = v;
        }
        __syncthreads();
        float ck = cks[step];
#pragma unroll
        for (int r = 0; r < 16; ++r) Sreg[r] = fmaf(ck, dst[tid + (r << 8)], Sreg[r]);
        prev = cur;
        cur = dst;
        __syncthreads();
    }

    // fused linear head
    float p[11];
#pragma unroll
    for (int j = 0; j < 11; ++j) p[j] = 0.f;
#pragma unroll
    for (int r = 0; r < 16; ++r) {
        int e = tid + (r << 8);
        float sv = Sreg[r];
#pragma unroll
        for (int j = 0; j < 11; ++j) p[j] = fmaf(sv, lw[j * 4096 + e], p[j]);
    }
#pragma unroll
    for (int j = 0; j < 11; ++j) red[j * 256 + tid] = p[j];
    __syncthreads();
    for (int s2 = 128; s2 > 0; s2 >>= 1) {
        if (tid < s2)
            for (int j = 0; j < 11; ++j)
                red[j * 256 + tid] += red[j * 256 + tid + s2];
        __syncthreads();
    }
    if (tid < 11) out[b * 11 + tid] = red[tid * 256] + lb[tid];
}

extern "C" void kernel_launch(void* const* d_in, const int* in_sizes, int n_in,
                              void* d_out, int out_size, void* d_ws, size_t ws_size,
                              hipStream_t stream) {
    const float* x    = (const float*)d_in[0];
    const float* W1   = (const float*)d_in[1];
    const float* W2   = (const float*)d_in[2];
    const float* W3   = (const float*)d_in[3];
    const float* W4   = (const float*)d_in[4];
    const float* lw   = (const float*)d_in[5];
    const float* lb   = (const float*)d_in[6];
    float* out = (float*)d_out;

    float* ws = (float*)d_ws;
    float* T1 = ws + WS_T1;
    float* T2 = ws + WS_T2;
    float* Wc = ws + WS_WC;
    float* Gp = ws + WS_GP;
    float* Sp = ws + WS_SP;

    dim3 b16(16, 16);
    // Wc = W1 @ W2 @ W3 @ W4  (fold small side first)
    mm_naive<<<dim3(128 / 16, 512 / 16), b16, 0, stream>>>(W2, W3, T1, 512, 256, 128);
    mm_naive<<<dim3(64 / 16, 512 / 16),  b16, 0, stream>>>(T1, W4, T2, 512, 128, 64);
    mm_naive<<<dim3(64 / 16, 1024 / 16), b16, 0, stream>>>(W1, T2, Wc, 1024, 512, 64);

    zgram<<<dim3(NCHUNK, 64), 256, 0, stream>>>(x, Wc, Gp, Sp);
    logeig_head<<<64, 256, 0, stream>>>(Gp, Sp, lw, lb, out);
}

// Round 4
// 640.029 us; speedup vs baseline: 1.2861x; 1.1978x over previous
//
#include <hip/hip_runtime.h>

// ---------------- workspace layout (float offsets) ----------------
#define WS_T1 0            // 512*128
#define WS_T2 65536        // 512*64
#define WS_WC 98304        // 1024*64
#define WS_GP 163840       // 19*64*4096 = 4980736
#define WS_SP 5144576      // 19*64*64   = 77824
// total 5222400 floats ~= 20.9 MiB

#define NCHUNK 19          // 19 chunks of 64 t cover 1200 (last chunk 48 valid)

// Chebyshev for log(x) on [0.5, 1.7]; x = 1.1 + 0.6u, t = -0.2967425904
#define CHEB_C0 0.0109173f
#define CHEB_C1 0.5934852f

// ---------------- small matmul, ILP-unrolled: C[MxN] = A[MxK] @ B[KxN] ----------------
// K % 8 == 0. One thread per output; 8 B-loads + 2 A-float4 in flight per group.
__global__ __launch_bounds__(256) void mm_fast(const float* __restrict__ A,
                                               const float* __restrict__ B,
                                               float* __restrict__ C,
                                               int M, int K, int N) {
    int n = blockIdx.x * 16 + threadIdx.x;
    int m = blockIdx.y * 16 + threadIdx.y;
    if (m >= M || n >= N) return;
    const float* Ar = A + (size_t)m * K;
    float acc = 0.f;
    for (int k = 0; k < K; k += 8) {
        float4 a0 = *(const float4*)&Ar[k];
        float4 a1 = *(const float4*)&Ar[k + 4];
        float b0 = B[(k + 0) * N + n];
        float b1 = B[(k + 1) * N + n];
        float b2 = B[(k + 2) * N + n];
        float b3 = B[(k + 3) * N + n];
        float b4 = B[(k + 4) * N + n];
        float b5 = B[(k + 5) * N + n];
        float b6 = B[(k + 6) * N + n];
        float b7 = B[(k + 7) * N + n];
        acc = fmaf(a0.x, b0, acc);
        acc = fmaf(a0.y, b1, acc);
        acc = fmaf(a0.z, b2, acc);
        acc = fmaf(a0.w, b3, acc);
        acc = fmaf(a1.x, b4, acc);
        acc = fmaf(a1.y, b5, acc);
        acc = fmaf(a1.z, b6, acc);
        acc = fmaf(a1.w, b7, acc);
    }
    C[(size_t)m * N + n] = acc;
}

// ---------------- fused Z-projection + partial Gram ----------------
// grid (19 t-chunks, 64 b), block 256 = 4 waves.
// Wave wv handles k in [256*wv, 256*wv+256) for all 64 o, lane owns t = ch*64+lane.
// k-loop unrolled x8 with explicit x prefetch to cover HBM latency.
__global__ __launch_bounds__(256) void zgram(const float* __restrict__ x,
                                             const float* __restrict__ Wc,
                                             float* __restrict__ Gp,
                                             float* __restrict__ Sp) {
    __shared__ __attribute__((aligned(16))) float zt[64][68];  // [t_local][o], pad 68
    const int ch = blockIdx.x, b = blockIdx.y;
    const int tid  = threadIdx.x;
    const int lane = tid & 63;
    const int wv   = __builtin_amdgcn_readfirstlane(tid >> 6);  // uniform wave id
    const int t  = ch * 64 + lane;
    const int tc = (t < 1200) ? t : 1199;  // clamp: duplicate read, zeroed later
    const float* xp = x + ((size_t)b * 1024 + (size_t)wv * 256) * 1200 + tc;
    const float* wp = Wc + wv * 256 * 64;  // wave-uniform -> scalar loads

    float acc[64];
#pragma unroll
    for (int j = 0; j < 64; ++j) acc[j] = 0.f;

    for (int k0 = 0; k0 < 256; k0 += 8) {
        float xv[8];
#pragma unroll
        for (int u = 0; u < 8; ++u) xv[u] = xp[(size_t)(k0 + u) * 1200];
#pragma unroll
        for (int u = 0; u < 8; ++u) {
            const float* wr = wp + (k0 + u) * 64;
#pragma unroll
            for (int j = 0; j < 64; ++j) acc[j] = fmaf(wr[j], xv[u], acc[j]);
        }
    }
    if (t >= 1200) {
#pragma unroll
        for (int j = 0; j < 64; ++j) acc[j] = 0.f;
    }

    // cross-wave k-reduction into one LDS tile (4 short phases)
    for (int w = 0; w < 4; ++w) {
        if (wv == w) {
            if (w == 0) {
#pragma unroll
                for (int j = 0; j < 64; ++j) zt[lane][j] = acc[j];
            } else {
#pragma unroll
                for (int j = 0; j < 64; ++j) zt[lane][j] += acc[j];
            }
        }
        __syncthreads();
    }

    // partial row sums (for mean centering)
    if (tid < 64) {
        float s = 0.f;
        for (int tt = 0; tt < 64; ++tt) s += zt[tt][tid];
        Sp[(ch * 64 + b) * 64 + tid] = s;
    }

    // partial Gram over this 64-t chunk: 4x4 outputs per thread
    const int tx = tid & 15, ty = tid >> 4;
    float g[4][4] = {};
    for (int tt = 0; tt < 64; ++tt) {
        float4 a  = *(const float4*)&zt[tt][4 * ty];
        float4 bb = *(const float4*)&zt[tt][4 * tx];
        const float* ap = (const float*)&a;
        const float* bp = (const float*)&bb;
#pragma unroll
        for (int r = 0; r < 4; ++r)
#pragma unroll
            for (int c = 0; c < 4; ++c)
                g[r][c] = fmaf(ap[r], bp[c], g[r][c]);
    }
    float* gp = Gp + ((size_t)(ch * 64 + b) << 12);
#pragma unroll
    for (int r = 0; r < 4; ++r) {
        float4 v;
        float* vp = (float*)&v;
#pragma unroll
        for (int c = 0; c < 4; ++c) vp[c] = g[r][c];
        *(float4*)&gp[(4 * ty + r) * 64 + 4 * tx] = v;
    }
}

// ---------------- per-batch: Y -> log(Y) via Chebyshev -> linear head ----------------
// grid 64, block 256
__global__ __launch_bounds__(256) void logeig_head(const float* __restrict__ Gp,
                                                   const float* __restrict__ sp,
                                                   const float* __restrict__ lw,
                                                   const float* __restrict__ lb,
                                                   float* __restrict__ out) {
    __shared__ __attribute__((aligned(16))) float BU[4096];
    __shared__ __attribute__((aligned(16))) float Bu0[4096];
    __shared__ __attribute__((aligned(16))) float Bu1[4096];
    __shared__ float svec[64];
    __shared__ float red[11 * 256];

    const int b = blockIdx.x, tid = threadIdx.x;

    if (tid < 64) {
        float s = 0.f;
        for (int c = 0; c < NCHUNK; ++c) s += sp[(c * 64 + b) * 64 + tid];
        svec[tid] = s;
    }
    __syncthreads();

    // reduce partial Grams, form U = (Y - 1.1 I)/0.6; S init = c0*I + c1*U
    float Sreg[16];
    const float inv1200 = 1.f / 1200.f, inv1199 = 1.f / 1199.f, invmw = 1.f / 0.6f;
#pragma unroll
    for (int r = 0; r < 16; ++r) {
        int e = tid + (r << 8);
        float gsum = 0.f;
        for (int c = 0; c < NCHUNK; ++c) gsum += Gp[((size_t)(c * 64 + b) << 12) + e];
        int row = e >> 6, col = e & 63;
        float y = (gsum - svec[row] * svec[col] * inv1200) * inv1199;
        float u = (y - (row == col ? 1.1f : 0.f)) * invmw;
        BU[e] = u;
        Sreg[r] = (row == col ? CHEB_C0 : 0.f) + CHEB_C1 * u;
    }
    __syncthreads();

    // ck = -2 t^k / k, k = 2..10 (truncation ~4e-7, far under threshold)
    const float cks[9] = {
        -0.0880562f,   0.0174200f,  -0.0038769f,   0.00092038f, -0.000227593f,
         5.78886e-5f, -1.50307e-5f,  3.96467e-6f, -1.05886e-6f };

    const int tx = tid & 15, ty = tid >> 4;
    float* cur = BU;
    float* prev = BU;  // dummy at step 0 (subtrahend is I there)
    for (int step = 0; step < 9; ++step) {
        float* dst = (step == 0) ? Bu0 : (step == 1) ? Bu1 : prev;
        float acc[4][4] = {};
#pragma unroll 4
        for (int k = 0; k < 64; ++k) {
            float4 a  = *(const float4*)&BU[k * 64 + 4 * ty];   // U symmetric
            float4 bb = *(const float4*)&cur[k * 64 + 4 * tx];
            const float* ap = (const float*)&a;
            const float* bp = (const float*)&bb;
#pragma unroll
            for (int r = 0; r < 4; ++r)
#pragma unroll
                for (int c = 0; c < 4; ++c)
                    acc[r][c] = fmaf(ap[r], bp[c], acc[r][c]);
        }
#pragma unroll
        for (int r = 0; r < 4; ++r) {
            int base = (4 * ty + r) * 64 + 4 * tx;
            float4 v;
            float* vp = (float*)&v;
#pragma unroll
            for (int c = 0; c < 4; ++c) {
                float pv = (step == 0) ? ((4 * ty + r) == (4 * tx + c) ? 1.f : 0.f)
                                       : prev[base + c];
                vp[c] = 2.f * acc[r][c] - pv;
            }
            *(float4*)&dst[base] = v;
        }
        __syncthreads();
        float ck = cks[step];
#pragma unroll
        for (int r = 0; r < 16; ++r) Sreg[r] = fmaf(ck, dst[tid + (r << 8)], Sreg[r]);
        prev = cur;
        cur = dst;
        __syncthreads();
    }

    // fused linear head
    float p[11];
#pragma unroll
    for (int j = 0; j < 11; ++j) p[j] = 0.f;
#pragma unroll
    for (int r = 0; r < 16; ++r) {
        int e = tid + (r << 8);
        float sv = Sreg[r];
#pragma unroll
        for (int j = 0; j < 11; ++j) p[j] = fmaf(sv, lw[j * 4096 + e], p[j]);
    }
#pragma unroll
    for (int j = 0; j < 11; ++j) red[j * 256 + tid] = p[j];
    __syncthreads();
    for (int s2 = 128; s2 > 0; s2 >>= 1) {
        if (tid < s2)
            for (int j = 0; j < 11; ++j)
                red[j * 256 + tid] += red[j * 256 + tid + s2];
        __syncthreads();
    }
    if (tid < 11) out[b * 11 + tid] = red[tid * 256] + lb[tid];
}

extern "C" void kernel_launch(void* const* d_in, const int* in_sizes, int n_in,
                              void* d_out, int out_size, void* d_ws, size_t ws_size,
                              hipStream_t stream) {
    const float* x    = (const float*)d_in[0];
    const float* W1   = (const float*)d_in[1];
    const float* W2   = (const float*)d_in[2];
    const float* W3   = (const float*)d_in[3];
    const float* W4   = (const float*)d_in[4];
    const float* lw   = (const float*)d_in[5];
    const float* lb   = (const float*)d_in[6];
    float* out = (float*)d_out;

    float* ws = (float*)d_ws;
    float* T1 = ws + WS_T1;
    float* T2 = ws + WS_T2;
    float* Wc = ws + WS_WC;
    float* Gp = ws + WS_GP;
    float* Sp = ws + WS_SP;

    dim3 b16(16, 16);
    // Wc = W1 @ W2 @ W3 @ W4  (fold small side first)
    mm_fast<<<dim3(128 / 16, 512 / 16), b16, 0, stream>>>(W2, W3, T1, 512, 256, 128);
    mm_fast<<<dim3(64 / 16, 512 / 16),  b16, 0, stream>>>(T1, W4, T2, 512, 128, 64);
    mm_fast<<<dim3(64 / 16, 1024 / 16), b16, 0, stream>>>(W1, T2, Wc, 1024, 512, 64);

    zgram<<<dim3(NCHUNK, 64), 256, 0, stream>>>(x, Wc, Gp, Sp);
    logeig_head<<<64, 256, 0, stream>>>(Gp, Sp, lw, lb, out);
}

// Round 5
// 565.175 us; speedup vs baseline: 1.4564x; 1.1324x over previous
//
#include <hip/hip_runtime.h>

// ---------------- workspace layout (float offsets) ----------------
#define WS_T1 0            // 512*128
#define WS_T2 65536        // 512*64
#define WS_WC 98304        // 1024*64
#define WS_GP 163840       // 19*64*4096 = 4980736
#define WS_SP 5144576      // 19*64*64   = 77824

#define NCHUNK 19          // 19 chunks of 64 t cover 1200 (last chunk 48 valid)

// Chebyshev for log(x) on [0.5, 1.7]; x = 1.1 + 0.6u, t = -0.2967425904
#define CHEB_C0 0.0109173f
#define CHEB_C1 0.5934852f

// ---------------- small matmul, ILP-unrolled: C[MxN] = A[MxK] @ B[KxN] ----------------
__global__ __launch_bounds__(256) void mm_fast(const float* __restrict__ A,
                                               const float* __restrict__ B,
                                               float* __restrict__ C,
                                               int M, int K, int N) {
    int n = blockIdx.x * 16 + threadIdx.x;
    int m = blockIdx.y * 16 + threadIdx.y;
    if (m >= M || n >= N) return;
    const float* Ar = A + (size_t)m * K;
    float acc = 0.f;
    for (int k = 0; k < K; k += 8) {
        float4 a0 = *(const float4*)&Ar[k];
        float4 a1 = *(const float4*)&Ar[k + 4];
        float b0 = B[(k + 0) * N + n];
        float b1 = B[(k + 1) * N + n];
        float b2 = B[(k + 2) * N + n];
        float b3 = B[(k + 3) * N + n];
        float b4 = B[(k + 4) * N + n];
        float b5 = B[(k + 5) * N + n];
        float b6 = B[(k + 6) * N + n];
        float b7 = B[(k + 7) * N + n];
        acc = fmaf(a0.x, b0, acc);
        acc = fmaf(a0.y, b1, acc);
        acc = fmaf(a0.z, b2, acc);
        acc = fmaf(a0.w, b3, acc);
        acc = fmaf(a1.x, b4, acc);
        acc = fmaf(a1.y, b5, acc);
        acc = fmaf(a1.z, b6, acc);
        acc = fmaf(a1.w, b7, acc);
    }
    C[(size_t)m * N + n] = acc;
}

// ---------------- fused Z-projection + partial Gram ----------------
// grid (19 t-chunks, 64 b), block 256 = 4 waves.
// Wave wv owns o in [16*wv, 16*wv+16) over the FULL k=1024; lane owns t.
// acc[16] per thread -> no VGPR spill (R4's acc[64] spilled at VGPR_Count=52).
// No cross-wave reduction: each wave writes its own o-columns to LDS.
__global__ __launch_bounds__(256) void zgram(const float* __restrict__ x,
                                             const float* __restrict__ Wc,
                                             float* __restrict__ Gp,
                                             float* __restrict__ Sp) {
    __shared__ __attribute__((aligned(16))) float zt[64][68];  // [t_local][o], pad 68
    const int ch = blockIdx.x, b = blockIdx.y;
    const int tid  = threadIdx.x;
    const int lane = tid & 63;
    const int wv   = __builtin_amdgcn_readfirstlane(tid >> 6);  // uniform wave id
    const int t  = ch * 64 + lane;
    const int tc = (t < 1200) ? t : 1199;  // clamp: duplicate read, zeroed later
    const float* xp = x + (size_t)b * 1024 * 1200 + tc;
    const float* wp = Wc + wv * 16;        // wave-uniform -> scalar loads

    float acc[16];
#pragma unroll
    for (int j = 0; j < 16; ++j) acc[j] = 0.f;

    for (int k0 = 0; k0 < 1024; k0 += 8) {
        float xv[8];
#pragma unroll
        for (int u = 0; u < 8; ++u) xv[u] = xp[(size_t)(k0 + u) * 1200];
#pragma unroll
        for (int u = 0; u < 8; ++u) {
            const float* wr = wp + (k0 + u) * 64;  // wave-uniform row
#pragma unroll
            for (int j = 0; j < 16; ++j) acc[j] = fmaf(wr[j], xv[u], acc[j]);
        }
    }
    if (t >= 1200) {
#pragma unroll
        for (int j = 0; j < 16; ++j) acc[j] = 0.f;
    }

    // each wave writes its disjoint o-columns; single barrier
#pragma unroll
    for (int j = 0; j < 16; ++j) zt[lane][wv * 16 + j] = acc[j];
    __syncthreads();

    // partial row sums (for mean centering)
    if (tid < 64) {
        float s = 0.f;
        for (int tt = 0; tt < 64; ++tt) s += zt[tt][tid];
        Sp[(ch * 64 + b) * 64 + tid] = s;
    }

    // partial Gram over this 64-t chunk: 4x4 outputs per thread
    const int tx = tid & 15, ty = tid >> 4;
    float g[4][4] = {};
    for (int tt = 0; tt < 64; ++tt) {
        float4 a  = *(const float4*)&zt[tt][4 * ty];
        float4 bb = *(const float4*)&zt[tt][4 * tx];
        const float* ap = (const float*)&a;
        const float* bp = (const float*)&bb;
#pragma unroll
        for (int r = 0; r < 4; ++r)
#pragma unroll
            for (int c = 0; c < 4; ++c)
                g[r][c] = fmaf(ap[r], bp[c], g[r][c]);
    }
    float* gp = Gp + ((size_t)(ch * 64 + b) << 12);
#pragma unroll
    for (int r = 0; r < 4; ++r) {
        float4 v;
        float* vp = (float*)&v;
#pragma unroll
        for (int c = 0; c < 4; ++c) vp[c] = g[r][c];
        *(float4*)&gp[(4 * ty + r) * 64 + 4 * tx] = v;
    }
}

// ---------------- per-batch: Y -> log(Y) via Chebyshev -> linear head ----------------
// grid 64, block 256
__global__ __launch_bounds__(256) void logeig_head(const float* __restrict__ Gp,
                                                   const float* __restrict__ sp,
                                                   const float* __restrict__ lw,
                                                   const float* __restrict__ lb,
                                                   float* __restrict__ out) {
    __shared__ __attribute__((aligned(16))) float BU[4096];
    __shared__ __attribute__((aligned(16))) float Bu0[4096];
    __shared__ __attribute__((aligned(16))) float Bu1[4096];
    __shared__ float svec[64];
    __shared__ float red[11 * 256];

    const int b = blockIdx.x, tid = threadIdx.x;

    if (tid < 64) {
        float s = 0.f;
        for (int c = 0; c < NCHUNK; ++c) s += sp[(c * 64 + b) * 64 + tid];
        svec[tid] = s;
    }
    __syncthreads();

    float Sreg[16];
    const float inv1200 = 1.f / 1200.f, inv1199 = 1.f / 1199.f, invmw = 1.f / 0.6f;
#pragma unroll
    for (int r = 0; r < 16; ++r) {
        int e = tid + (r << 8);
        float gsum = 0.f;
        for (int c = 0; c < NCHUNK; ++c) gsum += Gp[((size_t)(c * 64 + b) << 12) + e];
        int row = e >> 6, col = e & 63;
        float y = (gsum - svec[row] * svec[col] * inv1200) * inv1199;
        float u = (y - (row == col ? 1.1f : 0.f)) * invmw;
        BU[e] = u;
        Sreg[r] = (row == col ? CHEB_C0 : 0.f) + CHEB_C1 * u;
    }
    __syncthreads();

    // ck = -2 t^k / k, k = 2..10 (truncation ~4e-7, far under threshold)
    const float cks[9] = {
        -0.0880562f,   0.0174200f,  -0.0038769f,   0.00092038f, -0.000227593f,
         5.78886e-5f, -1.50307e-5f,  3.96467e-6f, -1.05886e-6f };

    const int tx = tid & 15, ty = tid >> 4;
    float* cur = BU;
    float* prev = BU;  // dummy at step 0 (subtrahend is I there)
    for (int step = 0; step < 9; ++step) {
        float* dst = (step == 0) ? Bu0 : (step == 1) ? Bu1 : prev;
        float acc[4][4] = {};
#pragma unroll 4
        for (int k = 0; k < 64; ++k) {
            float4 a  = *(const float4*)&BU[k * 64 + 4 * ty];   // U symmetric
            float4 bb = *(const float4*)&cur[k * 64 + 4 * tx];
            const float* ap = (const float*)&a;
            const float* bp = (const float*)&bb;
#pragma unroll
            for (int r = 0; r < 4; ++r)
#pragma unroll
                for (int c = 0; c < 4; ++c)
                    acc[r][c] = fmaf(ap[r], bp[c], acc[r][c]);
        }
#pragma unroll
        for (int r = 0; r < 4; ++r) {
            int base = (4 * ty + r) * 64 + 4 * tx;
            float4 v;
            float* vp = (float*)&v;
#pragma unroll
            for (int c = 0; c < 4; ++c) {
                float pv = (step == 0) ? ((4 * ty + r) == (4 * tx + c) ? 1.f : 0.f)
                                       : prev[base + c];
                vp[c] = 2.f * acc[r][c] - pv;
            }
            *(float4*)&dst[base] = v;
        }
        __syncthreads();
        float ck = cks[step];
#pragma unroll
        for (int r = 0; r < 16; ++r) Sreg[r] = fmaf(ck, dst[tid + (r << 8)], Sreg[r]);
        prev = cur;
        cur = dst;
        __syncthreads();
    }

    // fused linear head
    float p[11];
#pragma unroll
    for (int j = 0; j < 11; ++j) p[j] = 0.f;
#pragma unroll
    for (int r = 0; r < 16; ++r) {
        int e = tid + (r << 8);
        float sv = Sreg[r];
#pragma unroll
        for (int j = 0; j < 11; ++j) p[j] = fmaf(sv, lw[j * 4096 + e], p[j]);
    }
#pragma unroll
    for (int j = 0; j < 11; ++j) red[j * 256 + tid] = p[j];
    __syncthreads();
    for (int s2 = 128; s2 > 0; s2 >>= 1) {
        if (tid < s2)
            for (int j = 0; j < 11; ++j)
                red[j * 256 + tid] += red[j * 256 + tid + s2];
        __syncthreads();
    }
    if (tid < 11) out[b * 11 + tid] = red[tid * 256] + lb[tid];
}

extern "C" void kernel_launch(void* const* d_in, const int* in_sizes, int n_in,
                              void* d_out, int out_size, void* d_ws, size_t ws_size,
                              hipStream_t stream) {
    const float* x    = (const float*)d_in[0];
    const float* W1   = (const float*)d_in[1];
    const float* W2   = (const float*)d_in[2];
    const float* W3   = (const float*)d_in[3];
    const float* W4   = (const float*)d_in[4];
    const float* lw   = (const float*)d_in[5];
    const float* lb   = (const float*)d_in[6];
    float* out = (float*)d_out;

    float* ws = (float*)d_ws;
    float* T1 = ws + WS_T1;
    float* T2 = ws + WS_T2;
    float* Wc = ws + WS_WC;
    float* Gp = ws + WS_GP;
    float* Sp = ws + WS_SP;

    dim3 b16(16, 16);
    // Wc = W1 @ W2 @ W3 @ W4  (fold small side first)
    mm_fast<<<dim3(128 / 16, 512 / 16), b16, 0, stream>>>(W2, W3, T1, 512, 256, 128);
    mm_fast<<<dim3(64 / 16, 512 / 16),  b16, 0, stream>>>(T1, W4, T2, 512, 128, 64);
    mm_fast<<<dim3(64 / 16, 1024 / 16), b16, 0, stream>>>(W1, T2, Wc, 1024, 512, 64);

    zgram<<<dim3(NCHUNK, 64), 256, 0, stream>>>(x, Wc, Gp, Sp);
    logeig_head<<<64, 256, 0, stream>>>(Gp, Sp, lw, lb, out);
}